// Round 1
// baseline (276.051 us; speedup 1.0000x reference)
//
#include <hip/hip_runtime.h>

#define NPTS 2048
#define NPATCH 32
#define PTS_PER_PATCH 64          // 2048 / 32
#define FLOATS_PER_BATCH (NPTS*3) // 6144
#define N_PAIRS 528.0f            // 32*33/2

// Stage 1: one block per batch element. 256 threads.
// Thread t: patch = t>>3, sub = t&7, owns 8 consecutive points
// (patch*64 + sub*8 .. +7)  -> contiguous 96 bytes at offset t*96.
__global__ __launch_bounds__(256) void patch_stage1(
    const float* __restrict__ pcs, float* __restrict__ ws) {
  const int b   = blockIdx.x;
  const int tid = threadIdx.x;

  const float* base = pcs + (size_t)b * FLOATS_PER_BATCH;
  // 24 floats per thread = 6 float4 (base is 16B aligned: t*96 bytes)
  const float4* p4 = (const float4*)(base + tid * 24);

  float f[24];
#pragma unroll
  for (int k = 0; k < 6; ++k) {
    float4 v = p4[k];
    f[4*k+0] = v.x; f[4*k+1] = v.y; f[4*k+2] = v.z; f[4*k+3] = v.w;
  }

  float sx = 0.f, sy = 0.f, sz = 0.f;
  float sxx = 0.f, syy = 0.f, szz = 0.f;
#pragma unroll
  for (int k = 0; k < 8; ++k) {
    float x = f[3*k+0], y = f[3*k+1], z = f[3*k+2];
    sx += x; sy += y; sz += z;
    sxx += x*x; syy += y*y; szz += z*z;
  }

  // reduce across the 8 threads of this patch (wave-aligned groups of 8)
#pragma unroll
  for (int off = 4; off >= 1; off >>= 1) {
    sx  += __shfl_down(sx,  off, 8);
    sy  += __shfl_down(sy,  off, 8);
    sz  += __shfl_down(sz,  off, 8);
    sxx += __shfl_down(sxx, off, 8);
    syy += __shfl_down(syy, off, 8);
    szz += __shfl_down(szz, off, 8);
  }

  __shared__ float smean[NPATCH][4];  // pad to 4 for bank spread
  __shared__ float sstd[NPATCH][4];

  if ((tid & 7) == 0) {
    const int p = tid >> 3;
    const float inv_n = 1.0f / PTS_PER_PATCH;
    const float inv_nm1 = 1.0f / (PTS_PER_PATCH - 1);
    float mx = sx * inv_n, my = sy * inv_n, mz = sz * inv_n;
    float vx = fmaxf((sxx - sx*sx*inv_n) * inv_nm1, 0.f);
    float vy = fmaxf((syy - sy*sy*inv_n) * inv_nm1, 0.f);
    float vz = fmaxf((szz - sz*sz*inv_n) * inv_nm1, 0.f);
    smean[p][0] = mx; smean[p][1] = my; smean[p][2] = mz;
    sstd[p][0] = sqrtf(vx); sstd[p][1] = sqrtf(vy); sstd[p][2] = sqrtf(vz);
  }
  __syncthreads();

  // Pair phase: 1024 (i,j) cells over 256 threads; count only i<=j.
  float acc = 0.f;
#pragma unroll
  for (int r = 0; r < 4; ++r) {
    const int q = tid + 256 * r;
    const int i = q >> 5;
    const int j = q & 31;
    if (i <= j) {
      float rx = fmaxf((sstd[i][0] + sstd[j][0]) - fabsf(smean[i][0] - smean[j][0]), 0.f);
      float ry = fmaxf((sstd[i][1] + sstd[j][1]) - fabsf(smean[i][1] - smean[j][1]), 0.f);
      float rz = fmaxf((sstd[i][2] + sstd[j][2]) - fabsf(smean[i][2] - smean[j][2]), 0.f);
      acc += sqrtf(rx*rx + ry*ry + rz*rz);
    }
  }

  // block reduce (4 waves)
#pragma unroll
  for (int off = 32; off >= 1; off >>= 1) acc += __shfl_down(acc, off);
  __shared__ float wpart[4];
  if ((tid & 63) == 0) wpart[tid >> 6] = acc;
  __syncthreads();
  if (tid == 0) ws[b] = wpart[0] + wpart[1] + wpart[2] + wpart[3];
}

// Stage 2: single block reduces B partials, applies scale, writes out[0].
__global__ __launch_bounds__(256) void patch_stage2(
    const float* __restrict__ ws, float* __restrict__ out, int B, float scale) {
  float acc = 0.f;
  for (int i = threadIdx.x; i < B; i += 256) acc += ws[i];
#pragma unroll
  for (int off = 32; off >= 1; off >>= 1) acc += __shfl_down(acc, off);
  __shared__ float wpart[4];
  if ((threadIdx.x & 63) == 0) wpart[threadIdx.x >> 6] = acc;
  __syncthreads();
  if (threadIdx.x == 0) out[0] = (wpart[0] + wpart[1] + wpart[2] + wpart[3]) * scale;
}

extern "C" void kernel_launch(void* const* d_in, const int* in_sizes, int n_in,
                              void* d_out, int out_size, void* d_ws, size_t ws_size,
                              hipStream_t stream) {
  const float* pcs = (const float*)d_in[0];
  float* out = (float*)d_out;
  float* ws  = (float*)d_ws;

  const int B = in_sizes[0] / FLOATS_PER_BATCH;  // 8192
  const float scale = 1.0f / (N_PAIRS * (float)B);

  patch_stage1<<<B, 256, 0, stream>>>(pcs, ws);
  patch_stage2<<<1, 256, 0, stream>>>(ws, out, B, scale);
}

// Round 2
// 275.580 us; speedup vs baseline: 1.0017x; 1.0017x over previous
//
#include <hip/hip_runtime.h>

#define NPTS 2048
#define NPATCH 32
#define PTS_PER_PATCH 64          // 2048 / 32
#define FLOATS_PER_BATCH (NPTS*3) // 6144
#define N_PAIRS 528.0f            // 32*33/2

// Stage 1: one block per batch element. 256 threads.
// Thread t: patch p = t>>3, sub s = t&7.
// Loads float4 index 48p + 8k + s (k=0..5): each 8-lane group reads a
// contiguous 128B chunk, 64B-aligned -> every touched cache line fully
// consumed by that instruction (16 lines/wave-instr vs 96 before).
// Coordinate of v[k] components rotates with (2k+s)%3; accumulate into a
// local frame L[m] = true coord (m+s)%3 using compile-time m=(2k+j)%3,
// un-rotate once at the end.
__global__ __launch_bounds__(256) void patch_stage1(
    const float* __restrict__ pcs, float* __restrict__ ws) {
  const int b   = blockIdx.x;
  const int tid = threadIdx.x;
  const int p   = tid >> 3;
  const int s   = tid & 7;

  const float4* p4 = (const float4*)(pcs + (size_t)b * FLOATS_PER_BATCH) + 48 * p + s;

  float4 v[6];
#pragma unroll
  for (int k = 0; k < 6; ++k) v[k] = p4[8 * k];

  float L0 = 0.f, L1 = 0.f, L2 = 0.f;
  float Q0 = 0.f, Q1 = 0.f, Q2 = 0.f;

#define ACC(k, a, bb, c)                                          \
  { float x = v[k].x, y = v[k].y, z = v[k].z, w = v[k].w;         \
    L##a += x + w; Q##a += x * x + w * w;                         \
    L##bb += y;    Q##bb += y * y;                                \
    L##c += z;     Q##c += z * z; }
  // m = (2k + j) % 3 for j=0(x),1(y),2(z); w shares m with x.
  ACC(0, 0, 1, 2)
  ACC(1, 2, 0, 1)
  ACC(2, 1, 2, 0)
  ACC(3, 0, 1, 2)
  ACC(4, 2, 0, 1)
  ACC(5, 1, 2, 0)
#undef ACC

  // Un-rotate: L[m] holds true coordinate (m + s) % 3.
  float sx, sy, sz, sxx, syy, szz;
  const int s3 = s % 3;
  if (s3 == 0)      { sx = L0; sy = L1; sz = L2; sxx = Q0; syy = Q1; szz = Q2; }
  else if (s3 == 1) { sx = L2; sy = L0; sz = L1; sxx = Q2; syy = Q0; szz = Q1; }
  else              { sx = L1; sy = L2; sz = L0; sxx = Q1; syy = Q2; szz = Q0; }

  // reduce across the 8 threads of this patch (wave-aligned groups of 8)
#pragma unroll
  for (int off = 4; off >= 1; off >>= 1) {
    sx  += __shfl_down(sx,  off, 8);
    sy  += __shfl_down(sy,  off, 8);
    sz  += __shfl_down(sz,  off, 8);
    sxx += __shfl_down(sxx, off, 8);
    syy += __shfl_down(syy, off, 8);
    szz += __shfl_down(szz, off, 8);
  }

  __shared__ float smean[NPATCH][4];
  __shared__ float sstd[NPATCH][4];

  if (s == 0) {
    const float inv_n = 1.0f / PTS_PER_PATCH;
    const float inv_nm1 = 1.0f / (PTS_PER_PATCH - 1);
    smean[p][0] = sx * inv_n; smean[p][1] = sy * inv_n; smean[p][2] = sz * inv_n;
    sstd[p][0] = sqrtf(fmaxf((sxx - sx * sx * inv_n) * inv_nm1, 0.f));
    sstd[p][1] = sqrtf(fmaxf((syy - sy * sy * inv_n) * inv_nm1, 0.f));
    sstd[p][2] = sqrtf(fmaxf((szz - sz * sz * inv_n) * inv_nm1, 0.f));
  }
  __syncthreads();

  // Pair phase: 1024 (i,j) cells over 256 threads; count only i<=j.
  float acc = 0.f;
#pragma unroll
  for (int r = 0; r < 4; ++r) {
    const int q = tid + 256 * r;
    const int i = q >> 5;
    const int j = q & 31;
    if (i <= j) {
      float rx = fmaxf((sstd[i][0] + sstd[j][0]) - fabsf(smean[i][0] - smean[j][0]), 0.f);
      float ry = fmaxf((sstd[i][1] + sstd[j][1]) - fabsf(smean[i][1] - smean[j][1]), 0.f);
      float rz = fmaxf((sstd[i][2] + sstd[j][2]) - fabsf(smean[i][2] - smean[j][2]), 0.f);
      acc += sqrtf(rx * rx + ry * ry + rz * rz);
    }
  }

  // block reduce (4 waves)
#pragma unroll
  for (int off = 32; off >= 1; off >>= 1) acc += __shfl_down(acc, off);
  __shared__ float wpart[4];
  if ((tid & 63) == 0) wpart[tid >> 6] = acc;
  __syncthreads();
  if (tid == 0) ws[b] = wpart[0] + wpart[1] + wpart[2] + wpart[3];
}

// Stage 2: single block reduces B partials, applies scale, writes out[0].
__global__ __launch_bounds__(256) void patch_stage2(
    const float* __restrict__ ws, float* __restrict__ out, int B, float scale) {
  float acc = 0.f;
  for (int i = threadIdx.x; i < B; i += 256) acc += ws[i];
#pragma unroll
  for (int off = 32; off >= 1; off >>= 1) acc += __shfl_down(acc, off);
  __shared__ float wpart[4];
  if ((threadIdx.x & 63) == 0) wpart[threadIdx.x >> 6] = acc;
  __syncthreads();
  if (threadIdx.x == 0) out[0] = (wpart[0] + wpart[1] + wpart[2] + wpart[3]) * scale;
}

extern "C" void kernel_launch(void* const* d_in, const int* in_sizes, int n_in,
                              void* d_out, int out_size, void* d_ws, size_t ws_size,
                              hipStream_t stream) {
  const float* pcs = (const float*)d_in[0];
  float* out = (float*)d_out;
  float* ws  = (float*)d_ws;

  const int B = in_sizes[0] / FLOATS_PER_BATCH;  // 8192
  const float scale = 1.0f / (N_PAIRS * (float)B);

  patch_stage1<<<B, 256, 0, stream>>>(pcs, ws);
  patch_stage2<<<1, 256, 0, stream>>>(ws, out, B, scale);
}

// Round 3
// 274.107 us; speedup vs baseline: 1.0071x; 1.0054x over previous
//
#include <hip/hip_runtime.h>

#define NPTS 2048
#define NPATCH 32
#define PTS_PER_PATCH 64            // 2048 / 32
#define FLOATS_PER_BATCH (NPTS*3)   // 6144
#define N_PAIRS 528.0f              // 32*33/2
#define BATCHES_PER_BLOCK 4

// Stage 1: one block per 4 batch elements (grid = B/4 = 2048, 256 threads).
// Thread t: patch p = t>>3, sub s = t&7.
// Loads float4 index 48p + 8k + s (k=0..5): each 8-lane group reads a
// contiguous 128B chunk, 64B-aligned -> every touched line fully consumed.
// Coordinate of v[k] components rotates with (2k+s)%3; accumulate into a
// local frame and un-rotate once (compile-time indices only).
// Pair-phase contribution accumulates in-register across the 4 batches so
// the block-reduce tail is paid once per block, not once per batch.
__global__ __launch_bounds__(256) void patch_stage1(
    const float* __restrict__ pcs, float* __restrict__ ws) {
  const int tid = threadIdx.x;
  const int p   = tid >> 3;
  const int s   = tid & 7;

  __shared__ float smean[NPATCH][4];
  __shared__ float sstd[NPATCH][4];

  float acc = 0.f;

#pragma unroll
  for (int m = 0; m < BATCHES_PER_BLOCK; ++m) {
    const int b = blockIdx.x + gridDim.x * m;
    const float4* p4 =
        (const float4*)(pcs + (size_t)b * FLOATS_PER_BATCH) + 48 * p + s;

    float4 v[6];
#pragma unroll
    for (int k = 0; k < 6; ++k) v[k] = p4[8 * k];

    float L0 = 0.f, L1 = 0.f, L2 = 0.f;
    float Q0 = 0.f, Q1 = 0.f, Q2 = 0.f;

#define ACC(k, a, bb, c)                                          \
    { float x = v[k].x, y = v[k].y, z = v[k].z, w = v[k].w;       \
      L##a += x + w; Q##a += x * x + w * w;                       \
      L##bb += y;    Q##bb += y * y;                              \
      L##c += z;     Q##c += z * z; }
    // m_idx = (2k + j) % 3 for j=0(x),1(y),2(z); w shares with x.
    ACC(0, 0, 1, 2)
    ACC(1, 2, 0, 1)
    ACC(2, 1, 2, 0)
    ACC(3, 0, 1, 2)
    ACC(4, 2, 0, 1)
    ACC(5, 1, 2, 0)
#undef ACC

    // Un-rotate: L[i] holds true coordinate (i + s) % 3.
    float sx, sy, sz, sxx, syy, szz;
    const int s3 = s % 3;
    if (s3 == 0)      { sx = L0; sy = L1; sz = L2; sxx = Q0; syy = Q1; szz = Q2; }
    else if (s3 == 1) { sx = L2; sy = L0; sz = L1; sxx = Q2; syy = Q0; szz = Q1; }
    else              { sx = L1; sy = L2; sz = L0; sxx = Q1; syy = Q2; szz = Q0; }

    // reduce across the 8 threads of this patch (wave-aligned groups of 8)
#pragma unroll
    for (int off = 4; off >= 1; off >>= 1) {
      sx  += __shfl_down(sx,  off, 8);
      sy  += __shfl_down(sy,  off, 8);
      sz  += __shfl_down(sz,  off, 8);
      sxx += __shfl_down(sxx, off, 8);
      syy += __shfl_down(syy, off, 8);
      szz += __shfl_down(szz, off, 8);
    }

    if (m > 0) __syncthreads();  // previous pair phase must finish reading LDS

    if (s == 0) {
      const float inv_n = 1.0f / PTS_PER_PATCH;
      const float inv_nm1 = 1.0f / (PTS_PER_PATCH - 1);
      smean[p][0] = sx * inv_n; smean[p][1] = sy * inv_n; smean[p][2] = sz * inv_n;
      sstd[p][0] = sqrtf(fmaxf((sxx - sx * sx * inv_n) * inv_nm1, 0.f));
      sstd[p][1] = sqrtf(fmaxf((syy - sy * sy * inv_n) * inv_nm1, 0.f));
      sstd[p][2] = sqrtf(fmaxf((szz - sz * sz * inv_n) * inv_nm1, 0.f));
    }
    __syncthreads();

    // Pair phase: 1024 (i,j) cells over 256 threads; count only i<=j.
#pragma unroll
    for (int r = 0; r < 4; ++r) {
      const int q = tid + 256 * r;
      const int i = q >> 5;
      const int j = q & 31;
      if (i <= j) {
        float rx = fmaxf((sstd[i][0] + sstd[j][0]) - fabsf(smean[i][0] - smean[j][0]), 0.f);
        float ry = fmaxf((sstd[i][1] + sstd[j][1]) - fabsf(smean[i][1] - smean[j][1]), 0.f);
        float rz = fmaxf((sstd[i][2] + sstd[j][2]) - fabsf(smean[i][2] - smean[j][2]), 0.f);
        acc += sqrtf(rx * rx + ry * ry + rz * rz);
      }
    }
  }

  // block reduce (4 waves) — once per block
#pragma unroll
  for (int off = 32; off >= 1; off >>= 1) acc += __shfl_down(acc, off);
  __shared__ float wpart[4];
  if ((tid & 63) == 0) wpart[tid >> 6] = acc;
  __syncthreads();
  if (tid == 0) ws[blockIdx.x] = wpart[0] + wpart[1] + wpart[2] + wpart[3];
}

// Stage 2: single block reduces the per-block partials, scales, writes out[0].
__global__ __launch_bounds__(256) void patch_stage2(
    const float* __restrict__ ws, float* __restrict__ out, int n, float scale) {
  float acc = 0.f;
  for (int i = threadIdx.x; i < n; i += 256) acc += ws[i];
#pragma unroll
  for (int off = 32; off >= 1; off >>= 1) acc += __shfl_down(acc, off);
  __shared__ float wpart[4];
  if ((threadIdx.x & 63) == 0) wpart[threadIdx.x >> 6] = acc;
  __syncthreads();
  if (threadIdx.x == 0) out[0] = (wpart[0] + wpart[1] + wpart[2] + wpart[3]) * scale;
}

extern "C" void kernel_launch(void* const* d_in, const int* in_sizes, int n_in,
                              void* d_out, int out_size, void* d_ws, size_t ws_size,
                              hipStream_t stream) {
  const float* pcs = (const float*)d_in[0];
  float* out = (float*)d_out;
  float* ws  = (float*)d_ws;

  const int B = in_sizes[0] / FLOATS_PER_BATCH;   // 8192
  const int nblocks = B / BATCHES_PER_BLOCK;      // 2048
  const float scale = 1.0f / (N_PAIRS * (float)B);

  patch_stage1<<<nblocks, 256, 0, stream>>>(pcs, ws);
  patch_stage2<<<1, 256, 0, stream>>>(ws, out, nblocks, scale);
}